// Round 4
// baseline (118.017 us; speedup 1.0000x reference)
//
#include <hip/hip_runtime.h>
#include <hip/hip_fp16.h>
#include <math.h>

#define BB 2
#define NN 2048
#define NP1 2049
#define DM 128
#define NH 8
#define DK 16
#define RWIN 4
#define GRID_W 64
#define QPB 4        /* queries per attn block */
#define CAND_PQ 160  /* per-query candidate cap; binom mean ~36, sd ~6 */

__device__ __forceinline__ void unpack8(uint4 r, float* f) {
    float2 t;
    t = __half22float2(*(const __half2*)&r.x); f[0] = t.x; f[1] = t.y;
    t = __half22float2(*(const __half2*)&r.y); f[2] = t.x; f[3] = t.y;
    t = __half22float2(*(const __half2*)&r.z); f[4] = t.x; f[5] = t.y;
    t = __half22float2(*(const __half2*)&r.w); f[6] = t.x; f[7] = t.y;
}

// ---------------- QKV projection ----------------
// R13: k-split redesign. R12's QKV_ROWS=16 halved W traffic (98MB) but
// dropped the grid to 257 blocks = 1.5 waves/SIMD -- no latency hiding
// (Guideline 1 violation). Same traffic, 4x the occupancy: QKV_ROWS=8,
// 768 threads = 3 mats x 2 kk-halves x 128 threads. Each 128-group does
// a partial GEMM over 64 k's (32KB W fetch; 192KB/block; x513 = 98MB),
// halves combine via 12KB LDS partials + 1 barrier. 513 blocks ~= 2/CU
// x 12 waves = 24 waves/CU = 6/SIMD.

#define QKV_ROWS 8

__global__ __launch_bounds__(768) void qkv_kernel(
    const float* __restrict__ z, const float* __restrict__ patch,
    const float* __restrict__ Wq, const float* __restrict__ bq,
    const float* __restrict__ Wk, const float* __restrict__ bk,
    const float* __restrict__ Wv, const float* __restrict__ bv,
    float* __restrict__ q, __half* __restrict__ k, __half* __restrict__ v) {
    __shared__ float zrow[QKV_ROWS][DM];
    __shared__ float pacc[3][QKV_ROWS][DM];   // kk-half-1 partials
    const int tid = threadIdx.x;
    const int mat  = tid >> 8;         // 0=q 1=k 2=v (4 waves each)
    const int half = (tid >> 7) & 1;   // kk range [64*half, 64*half+64)
    const int rem  = tid & 127;
    const int cg = rem & 31;           // cols cg*4..cg*4+3
    const int rs = rem >> 5;           // rows rs, rs+4
    const int r0 = blockIdx.x * QKV_ROWS;
    const int NROWS = BB * NP1;

    if (tid < QKV_ROWS * DM / 4) {
        int r = tid >> 5, q4 = tid & 31;
        int row = r0 + r;
        float4 val = make_float4(0.f, 0.f, 0.f, 0.f);
        if (row < NROWS) {
            int b = row / NP1, ti = row % NP1;
            const float* src = (ti < NN) ? (z + ((size_t)b * NN + ti) * DM)
                                         : (patch + (size_t)b * DM);
            val = ((const float4*)src)[q4];
        }
        *((float4*)&zrow[r][q4 * 4]) = val;
    }
    __syncthreads();

    const float* W    = (mat == 0) ? Wq : (mat == 1) ? Wk : Wv;
    const float* bias = (mat == 0) ? bq : (mat == 1) ? bk : bv;
    const int k0 = half * 64;

    float4 a0 = make_float4(0.f, 0.f, 0.f, 0.f);
    float4 a1 = make_float4(0.f, 0.f, 0.f, 0.f);
#pragma unroll 4
    for (int kk4 = k0; kk4 < k0 + 64; kk4 += 4) {
        float4 zv0 = *((const float4*)&zrow[rs][kk4]);
        float4 zv1 = *((const float4*)&zrow[rs + 4][kk4]);
        const float* zp0 = (const float*)&zv0;
        const float* zp1 = (const float*)&zv1;
#pragma unroll
        for (int t = 0; t < 4; ++t) {
            float4 w4 = *((const float4*)(W + (size_t)(kk4 + t) * DM + cg * 4));
            float z0 = zp0[t], z1 = zp1[t];
            a0.x = fmaf(z0, w4.x, a0.x); a0.y = fmaf(z0, w4.y, a0.y);
            a0.z = fmaf(z0, w4.z, a0.z); a0.w = fmaf(z0, w4.w, a0.w);
            a1.x = fmaf(z1, w4.x, a1.x); a1.y = fmaf(z1, w4.y, a1.y);
            a1.z = fmaf(z1, w4.z, a1.z); a1.w = fmaf(z1, w4.w, a1.w);
        }
    }

    if (half == 1) {
        *((float4*)&pacc[mat][rs][cg * 4])     = a0;
        *((float4*)&pacc[mat][rs + 4][cg * 4]) = a1;
    }
    __syncthreads();

    if (half == 0) {
        float4 p0 = *((const float4*)&pacc[mat][rs][cg * 4]);
        float4 p1 = *((const float4*)&pacc[mat][rs + 4][cg * 4]);
        float4 b4 = *((const float4*)(bias + cg * 4));
        float4 o0 = make_float4(a0.x + p0.x + b4.x, a0.y + p0.y + b4.y,
                                a0.z + p0.z + b4.z, a0.w + p0.w + b4.w);
        float4 o1 = make_float4(a1.x + p1.x + b4.x, a1.y + p1.y + b4.y,
                                a1.z + p1.z + b4.z, a1.w + p1.w + b4.w);
#pragma unroll
        for (int rr = 0; rr < 2; ++rr) {
            int row = r0 + rs + rr * 4;
            if (row >= NROWS) break;
            float4 val = rr ? o1 : o0;
            int b = row / NP1, ti = row % NP1;
            if (mat == 0) {
                if (ti < NN) ((float4*)(q + ((size_t)b * NN + ti) * DM))[cg] = val;
            } else {
                __half2 p0h = __floats2half2_rn(val.x, val.y);
                __half2 p1h = __floats2half2_rn(val.z, val.w);
                uint2 st;
                st.x = *(unsigned int*)&p0h;
                st.y = *(unsigned int*)&p1h;
                __half* dst = ((mat == 1) ? k : v) + ((size_t)b * NP1 + ti) * DM;
                ((uint2*)dst)[cg] = st;
            }
        }
    }
}

// ---------------- fused: 4-query scan + sparse attention + out-proj ----------------
// (unchanged this round -- isolating the qkv redesign)
// grid 1024 blocks, 256 threads = 4 queries x 8 heads x 8 key-slots.
// fp16 K/V uint4 gathers; no-max softmax; slot-reduce via xor-shuffle tree
// (R10); cooperative Wo out-projection, Wo read once/block (R11, -5.2us);
// 2-key software-pipelined gather (R12).

__global__ __launch_bounds__(256) void attn_out_kernel(
    const float* __restrict__ q, const __half* __restrict__ k, const __half* __restrict__ v,
    const int* __restrict__ positions, const float* __restrict__ alive,
    const float* __restrict__ rel_bias, const float* __restrict__ Wo,
    const float* __restrict__ bo, float* __restrict__ out) {
    const int tid = threadIdx.x;
    const int qq = tid >> 6;          // 0..3 query in group (= wave id)
    const int l6 = tid & 63;
    const int h = l6 >> 3;            // 0..7 head
    const int s = l6 & 7;             // 0..7 key slot
    const int r0 = blockIdx.x * QPB;  // global query base (same batch: NN%QPB==0)
    const int b = r0 >> 11;
    const int bi = r0 + qq;

    __shared__ float sbias[NH * 81];
    __shared__ int   spx[QPB], spy[QPB];
    __shared__ float sal[QPB];
    __shared__ int   mcount[QPB];
    __shared__ int   cand[QPB][CAND_PQ];
    __shared__ float srow[QPB][DM];        // normalized attention output per query
    __shared__ float4 pw[QPB][QPB][32];    // [wave][query][colgroup] out-proj partials

    if (tid < QPB) {
        mcount[tid] = 0;
        int gbi = r0 + tid;
        spx[tid] = positions[gbi * 2 + 0];
        spy[tid] = positions[gbi * 2 + 1];
        sal[tid] = alive[gbi];
    }
    if (tid < NH * 81 / 4) ((float4*)sbias)[tid] = ((const float4*)rel_bias)[tid];

    const __half* kb = k + (size_t)b * NP1 * DM;
    const __half* vb = v + (size_t)b * NP1 * DM;

    // q segment for (query qq, head h), pre-scaled by 1/sqrt(dk)
    float qf[16];
    {
        const float4* qr = (const float4*)(q + (size_t)bi * DM + h * DK);
#pragma unroll
        for (int e = 0; e < 4; ++e) {
            float4 t4 = qr[e];
            qf[e * 4 + 0] = t4.x * 0.25f; qf[e * 4 + 1] = t4.y * 0.25f;
            qf[e * 4 + 2] = t4.z * 0.25f; qf[e * 4 + 3] = t4.w * 0.25f;
        }
    }

    __syncthreads(); // spos/sal/mcount/sbias visible

    int qx[QPB], qy[QPB], qi[QPB];
    float qa[QPB];
#pragma unroll
    for (int u = 0; u < QPB; ++u) {
        qx[u] = spx[u]; qy[u] = spy[u]; qa[u] = sal[u];
        qi[u] = (r0 + u) & (NN - 1);
    }

    // one scan over all agents, 4 query tests each
    {
        const int2* pb = (const int2*)(positions + (size_t)b * NN * 2);
        const float* ab = alive + (size_t)b * NN;
#pragma unroll
        for (int u = 0; u < NN / 256; ++u) {
            int j = u * 256 + tid;
            int2 pj = pb[j];
            float aj = ab[j];
            if (aj > 0.5f) {
                int packed = j | (pj.x << 16) | (pj.y << 24);
#pragma unroll
                for (int qn = 0; qn < QPB; ++qn) {
                    int dx = pj.x - qx[qn]; dx = dx < 0 ? -dx : dx;
                    int dy = pj.y - qy[qn]; dy = dy < 0 ? -dy : dy;
                    int ch = dx > dy ? dx : dy;
                    if (ch <= RWIN && j != qi[qn] && qa[qn] > 0.5f) {
                        int slot = atomicAdd(&mcount[qn], 1);
                        if (slot < CAND_PQ) cand[qn][slot] = packed;
                    }
                }
            }
        }
    }
    __syncthreads();
    int M = mcount[qq]; if (M > CAND_PQ) M = CAND_PQ;
    const int pix = qx[qq], piy = qy[qq];

    float l = 0.f;
    float o[16];
#pragma unroll
    for (int e = 0; e < 16; ++e) o[e] = 0.f;

    if (s == 0) { // patch column: always allowed, no bias; keeps l>0 for dead queries
        const uint4* kr = (const uint4*)(kb + (size_t)NN * DM + h * DK);
        uint4 ka = kr[0], kb4 = kr[1];
        const uint4* vr = (const uint4*)(vb + (size_t)NN * DM + h * DK);
        uint4 va = vr[0], vb4 = vr[1];
        float kf[16], vf[16];
        unpack8(ka, kf); unpack8(kb4, kf + 8);
        unpack8(va, vf); unpack8(vb4, vf + 8);
        float d = 0.f;
#pragma unroll
        for (int e = 0; e < 16; ++e) d = fmaf(qf[e], kf[e], d);
        float p = __expf(d);
        l += p;
#pragma unroll
        for (int e = 0; e < 16; ++e) o[e] = fmaf(p, vf[e], o[e]);
    }

    // 2-key software-pipelined gather: issue all loads for the pair, then compute
    for (int t = s; t < M; t += 16) {
        const int t1 = t + 8;
        const bool has1 = t1 < M;
        int packed0 = cand[qq][t];
        int packed1 = has1 ? cand[qq][t1] : packed0;
        int j0 = packed0 & 0xFFFF;
        int j1 = packed1 & 0xFFFF;

        const uint4* kr0 = (const uint4*)(kb + (size_t)j0 * DM + h * DK);
        const uint4* vr0 = (const uint4*)(vb + (size_t)j0 * DM + h * DK);
        const uint4* kr1 = (const uint4*)(kb + (size_t)j1 * DM + h * DK);
        const uint4* vr1 = (const uint4*)(vb + (size_t)j1 * DM + h * DK);
        uint4 k0a = kr0[0], k0b = kr0[1];
        uint4 v0a = vr0[0], v0b = vr0[1];
        uint4 k1a = kr1[0], k1b = kr1[1];
        uint4 v1a = vr1[0], v1b = vr1[1];

        // key 0
        {
            float kf[16], vf[16];
            unpack8(k0a, kf); unpack8(k0b, kf + 8);
            unpack8(v0a, vf); unpack8(v0b, vf + 8);
            float d = 0.f;
#pragma unroll
            for (int e = 0; e < 16; ++e) d = fmaf(qf[e], kf[e], d);
            int pjx = (packed0 >> 16) & 0xFF;
            int pjy = (packed0 >> 24) & 0xFF;
            float bias = sbias[h * 81 + (pjx - pix + RWIN) * 9 + (pjy - piy + RWIN)];
            float p = __expf(d + bias);
            l += p;
#pragma unroll
            for (int e = 0; e < 16; ++e) o[e] = fmaf(p, vf[e], o[e]);
        }
        // key 1
        if (has1) {
            float kf[16], vf[16];
            unpack8(k1a, kf); unpack8(k1b, kf + 8);
            unpack8(v1a, vf); unpack8(v1b, vf + 8);
            float d = 0.f;
#pragma unroll
            for (int e = 0; e < 16; ++e) d = fmaf(qf[e], kf[e], d);
            int pjx = (packed1 >> 16) & 0xFF;
            int pjy = (packed1 >> 24) & 0xFF;
            float bias = sbias[h * 81 + (pjx - pix + RWIN) * 9 + (pjy - piy + RWIN)];
            float p = __expf(d + bias);
            l += p;
#pragma unroll
            for (int e = 0; e < 16; ++e) o[e] = fmaf(p, vf[e], o[e]);
        }
    }

    // in-wave reduction over the 8 key-slot lanes: reduce + redistribute.
    // lane s ends with fully-reduced output elements {2s, 2s+1}.
    float r2_0, r2_1;
    {
        float r8[8];
        const bool hi4 = (s & 4) != 0;
#pragma unroll
        for (int e = 0; e < 8; ++e) {
            float a = o[e]     + __shfl_xor(o[e],     4, 64);
            float bq_ = o[e + 8] + __shfl_xor(o[e + 8], 4, 64);
            r8[e] = hi4 ? bq_ : a;
        }
        float r4[4];
        const bool hi2 = (s & 2) != 0;
#pragma unroll
        for (int e = 0; e < 4; ++e) {
            float a = r8[e]     + __shfl_xor(r8[e],     2, 64);
            float bq_ = r8[e + 4] + __shfl_xor(r8[e + 4], 2, 64);
            r4[e] = hi2 ? bq_ : a;
        }
        const bool hi1 = (s & 1) != 0;
#pragma unroll
        for (int e = 0; e < 2; ++e) {
            float a = r4[e]     + __shfl_xor(r4[e],     1, 64);
            float bq_ = r4[e + 2] + __shfl_xor(r4[e + 2], 1, 64);
            float r = hi1 ? bq_ : a;
            if (e == 0) r2_0 = r; else r2_1 = r;
        }
        l += __shfl_xor(l, 1, 64);
        l += __shfl_xor(l, 2, 64);
        l += __shfl_xor(l, 4, 64);
    }
    {
        float linv = 1.f / l;
        float2 st;
        st.x = r2_0 * linv;
        st.y = r2_1 * linv;
        *((float2*)&srow[qq][h * DK + s * 2]) = st;  // offset 2*l6: contiguous, conflict-free
    }
    __syncthreads();

    // ---- cooperative output projection: Wo read once per block ----
    // wave wv owns Wo rows [32wv, 32wv+32); lane: ks = l6>>5 (16-row half),
    // m = l6&31 (cols 4m..4m+3). Each w4 load feeds all 4 queries.
    {
        const int wv = qq;
        const int ks = l6 >> 5;
        const int m  = l6 & 31;
        const int kbase = wv * 32 + ks * 16;
        float4 acc[QPB];
#pragma unroll
        for (int oq = 0; oq < QPB; ++oq) acc[oq] = make_float4(0.f, 0.f, 0.f, 0.f);
#pragma unroll
        for (int r = 0; r < 16; ++r) {
            const int kk = kbase + r;
            float4 w4 = *((const float4*)(Wo + (size_t)kk * DM + m * 4));
#pragma unroll
            for (int oq = 0; oq < QPB; ++oq) {
                float sv = srow[oq][kk];   // broadcast within half-wave
                acc[oq].x = fmaf(sv, w4.x, acc[oq].x);
                acc[oq].y = fmaf(sv, w4.y, acc[oq].y);
                acc[oq].z = fmaf(sv, w4.z, acc[oq].z);
                acc[oq].w = fmaf(sv, w4.w, acc[oq].w);
            }
        }
        // fold the two 16-row halves (ks=0/1) via xor-shuffle across lane 32
#pragma unroll
        for (int oq = 0; oq < QPB; ++oq) {
            acc[oq].x += __shfl_xor(acc[oq].x, 32, 64);
            acc[oq].y += __shfl_xor(acc[oq].y, 32, 64);
            acc[oq].z += __shfl_xor(acc[oq].z, 32, 64);
            acc[oq].w += __shfl_xor(acc[oq].w, 32, 64);
        }
        if (ks == 0) {
#pragma unroll
            for (int oq = 0; oq < QPB; ++oq) pw[wv][oq][m] = acc[oq];
        }
    }
    __syncthreads();

    // final cross-wave reduction: 128 threads, one (query, colgroup) each
    if (tid < QPB * 32) {
        const int oq = tid >> 5;
        const int m  = tid & 31;
        float4 s0 = pw[0][oq][m], s1 = pw[1][oq][m];
        float4 s2 = pw[2][oq][m], s3 = pw[3][oq][m];
        float ga = sal[oq] > 0.5f ? 1.f : 0.f;
        float4 b4 = *((const float4*)(bo + m * 4));
        float4 r;
        r.x = (s0.x + s1.x + s2.x + s3.x + b4.x) * ga;
        r.y = (s0.y + s1.y + s2.y + s3.y + b4.y) * ga;
        r.z = (s0.z + s1.z + s2.z + s3.z + b4.z) * ga;
        r.w = (s0.w + s1.w + s2.w + s3.w + b4.w) * ga;
        ((float4*)(out + (size_t)(r0 + oq) * DM))[m] = r;
    }
}

extern "C" void kernel_launch(void* const* d_in, const int* in_sizes, int n_in,
                              void* d_out, int out_size, void* d_ws, size_t ws_size,
                              hipStream_t stream) {
    const float* z         = (const float*)d_in[0];
    const float* patch     = (const float*)d_in[1];
    const int*   positions = (const int*)d_in[2];
    const float* alive     = (const float*)d_in[3];
    const float* Wq        = (const float*)d_in[4];
    const float* bq        = (const float*)d_in[5];
    const float* Wk        = (const float*)d_in[6];
    const float* bk        = (const float*)d_in[7];
    const float* Wv        = (const float*)d_in[8];
    const float* bv        = (const float*)d_in[9];
    const float* Wo        = (const float*)d_in[10];
    const float* bo        = (const float*)d_in[11];
    const float* rel_bias  = (const float*)d_in[12];
    float* out = (float*)d_out;

    char* ws = (char*)d_ws;
    size_t off = 0;
    auto alloc = [&](size_t bytes) -> void* {
        void* p = ws + off;
        off += (bytes + 255) & ~(size_t)255;
        return p;
    };
    float*  q = (float*)alloc((size_t)BB * NN * DM * 4);
    __half* k = (__half*)alloc((size_t)BB * NP1 * DM * 2);
    __half* v = (__half*)alloc((size_t)BB * NP1 * DM * 2);

    qkv_kernel<<<(BB * NP1 + QKV_ROWS - 1) / QKV_ROWS, 768, 0, stream>>>(z, patch, Wq, bq, Wk, bk, Wv, bv, q, k, v);
    attn_out_kernel<<<(BB * NN) / QPB, 256, 0, stream>>>(q, k, v, positions, alive, rel_bias, Wo, bo, out);
}

// Round 5
// 115.946 us; speedup vs baseline: 1.0179x; 1.0179x over previous
//
#include <hip/hip_runtime.h>
#include <hip/hip_fp16.h>
#include <math.h>

#define BB 2
#define NN 2048
#define NP1 2049
#define DM 128
#define NH 8
#define DK 16
#define RWIN 4
#define GRID_W 64
#define QPB 4        /* queries per attn block */
#define CAND_PQ 160  /* per-query candidate cap; binom mean ~36, sd ~6 */

/* v_dot2_f32_f16: 2 fp16 products + f32 accumulate per instruction */
#if defined(__has_builtin)
#  if __has_builtin(__builtin_amdgcn_fdot2)
#    define USE_FDOT2 1
#  endif
#endif
#ifndef USE_FDOT2
#  define USE_FDOT2 0
#endif
typedef _Float16 f16x2 __attribute__((ext_vector_type(2)));

__device__ __forceinline__ void unpack8(uint4 r, float* f) {
    float2 t;
    t = __half22float2(*(const __half2*)&r.x); f[0] = t.x; f[1] = t.y;
    t = __half22float2(*(const __half2*)&r.y); f[2] = t.x; f[3] = t.y;
    t = __half22float2(*(const __half2*)&r.z); f[4] = t.x; f[5] = t.y;
    t = __half22float2(*(const __half2*)&r.w); f[6] = t.x; f[7] = t.y;
}

// ---------------- QKV projection ----------------
// R14: reverted to the R11 shape (QKV_ROWS=8, 384 threads, 2 rows/thread).
// R13's k-split was a modeling error: each 128-thread half still held 2
// waves both fetching the same W bytes -> traffic NOT halved, and the
// 768-thread block + extra barrier + 12KB LDS partials cost ~+6us.
// R12's 16-row variant traded occupancy (1.5 waves/SIMD) for traffic at a
// small net loss. This 8-row/384T shape is the best measured.

#define QKV_ROWS 8

__global__ __launch_bounds__(384) void qkv_kernel(
    const float* __restrict__ z, const float* __restrict__ patch,
    const float* __restrict__ Wq, const float* __restrict__ bq,
    const float* __restrict__ Wk, const float* __restrict__ bk,
    const float* __restrict__ Wv, const float* __restrict__ bv,
    float* __restrict__ q, __half* __restrict__ k, __half* __restrict__ v) {
    __shared__ float zrow[QKV_ROWS][DM];
    const int tid = threadIdx.x;
    const int mat = tid >> 7;          // 0=q 1=k 2=v, wave-uniform
    const int rem = tid & 127;
    const int cg = rem & 31;           // cols cg*4..cg*4+3
    const int rs = rem >> 5;           // rows rs, rs+4
    const int r0 = blockIdx.x * QKV_ROWS;
    const int NROWS = BB * NP1;

    if (tid < QKV_ROWS * DM / 4) {
        int r = tid >> 5, q4 = tid & 31;
        int row = r0 + r;
        float4 val = make_float4(0.f, 0.f, 0.f, 0.f);
        if (row < NROWS) {
            int b = row / NP1, ti = row % NP1;
            const float* src = (ti < NN) ? (z + ((size_t)b * NN + ti) * DM)
                                         : (patch + (size_t)b * DM);
            val = ((const float4*)src)[q4];
        }
        *((float4*)&zrow[r][q4 * 4]) = val;
    }
    __syncthreads();

    const float* W    = (mat == 0) ? Wq : (mat == 1) ? Wk : Wv;
    const float* bias = (mat == 0) ? bq : (mat == 1) ? bk : bv;

    float a0x = 0.f, a0y = 0.f, a0z = 0.f, a0w = 0.f;
    float a1x = 0.f, a1y = 0.f, a1z = 0.f, a1w = 0.f;
#pragma unroll 2
    for (int kk4 = 0; kk4 < DM; kk4 += 4) {
        float4 z0v = *((const float4*)&zrow[rs][kk4]);
        float4 z1v = *((const float4*)&zrow[rs + 4][kk4]);
        const float* zp0 = (const float*)&z0v;
        const float* zp1 = (const float*)&z1v;
#pragma unroll
        for (int t = 0; t < 4; ++t) {
            float4 w4 = *((const float4*)(W + (size_t)(kk4 + t) * DM + cg * 4));
            float z0 = zp0[t];
            float z1 = zp1[t];
            a0x = fmaf(z0, w4.x, a0x); a0y = fmaf(z0, w4.y, a0y);
            a0z = fmaf(z0, w4.z, a0z); a0w = fmaf(z0, w4.w, a0w);
            a1x = fmaf(z1, w4.x, a1x); a1y = fmaf(z1, w4.y, a1y);
            a1z = fmaf(z1, w4.z, a1z); a1w = fmaf(z1, w4.w, a1w);
        }
    }
    float4 b4 = *((const float4*)(bias + cg * 4));
    float4 o0 = make_float4(a0x + b4.x, a0y + b4.y, a0z + b4.z, a0w + b4.w);
    float4 o1 = make_float4(a1x + b4.x, a1y + b4.y, a1z + b4.z, a1w + b4.w);

#pragma unroll
    for (int rr = 0; rr < 2; ++rr) {
        int row = r0 + rs + rr * 4;
        if (row >= NROWS) break;
        float4 val = rr ? o1 : o0;
        int b = row / NP1, ti = row % NP1;
        if (mat == 0) {
            if (ti < NN) ((float4*)(q + ((size_t)b * NN + ti) * DM))[cg] = val;
        } else {
            __half2 p0 = __floats2half2_rn(val.x, val.y);
            __half2 p1 = __floats2half2_rn(val.z, val.w);
            uint2 st;
            st.x = *(unsigned int*)&p0;
            st.y = *(unsigned int*)&p1;
            __half* dst = ((mat == 1) ? k : v) + ((size_t)b * NP1 + ti) * DM;
            ((uint2*)dst)[cg] = st;
        }
    }
}

// ---------------- fused: 4-query scan + sparse attention + out-proj ----------------
// grid 1024 blocks, 256 threads = 4 queries x 8 heads x 8 key-slots.
// fp16 K/V uint4 gathers; no-max softmax; slot-reduce via xor-shuffle tree
// (R10); cooperative Wo out-projection, Wo read once/block (R11, -5.2us);
// 2-key software-pipelined gather (R12, ~-2us).
// R14 change: K-dot via v_dot2_f32_f16 (fdot2). q fragment pre-converted
// to 8x half2 once; each key's 16-elem dot = 8 fdot2 instead of 16 cvt +
// 16 fma. Guarded by __has_builtin with the unpack path as fallback.

__global__ __launch_bounds__(256) void attn_out_kernel(
    const float* __restrict__ q, const __half* __restrict__ k, const __half* __restrict__ v,
    const int* __restrict__ positions, const float* __restrict__ alive,
    const float* __restrict__ rel_bias, const float* __restrict__ Wo,
    const float* __restrict__ bo, float* __restrict__ out) {
    const int tid = threadIdx.x;
    const int qq = tid >> 6;          // 0..3 query in group (= wave id)
    const int l6 = tid & 63;
    const int h = l6 >> 3;            // 0..7 head
    const int s = l6 & 7;             // 0..7 key slot
    const int r0 = blockIdx.x * QPB;  // global query base (same batch: NN%QPB==0)
    const int b = r0 >> 11;
    const int bi = r0 + qq;

    __shared__ float sbias[NH * 81];
    __shared__ int   spx[QPB], spy[QPB];
    __shared__ float sal[QPB];
    __shared__ int   mcount[QPB];
    __shared__ int   cand[QPB][CAND_PQ];
    __shared__ float srow[QPB][DM];        // normalized attention output per query
    __shared__ float4 pw[QPB][QPB][32];    // [wave][query][colgroup] out-proj partials

    if (tid < QPB) {
        mcount[tid] = 0;
        int gbi = r0 + tid;
        spx[tid] = positions[gbi * 2 + 0];
        spy[tid] = positions[gbi * 2 + 1];
        sal[tid] = alive[gbi];
    }
    if (tid < NH * 81 / 4) ((float4*)sbias)[tid] = ((const float4*)rel_bias)[tid];

    const __half* kb = k + (size_t)b * NP1 * DM;
    const __half* vb = v + (size_t)b * NP1 * DM;

    // q segment for (query qq, head h), pre-scaled by 1/sqrt(dk)
    float qf[16];
    {
        const float4* qr = (const float4*)(q + (size_t)bi * DM + h * DK);
#pragma unroll
        for (int e = 0; e < 4; ++e) {
            float4 t4 = qr[e];
            qf[e * 4 + 0] = t4.x * 0.25f; qf[e * 4 + 1] = t4.y * 0.25f;
            qf[e * 4 + 2] = t4.z * 0.25f; qf[e * 4 + 3] = t4.w * 0.25f;
        }
    }
#if USE_FDOT2
    f16x2 qh[8];
#pragma unroll
    for (int e = 0; e < 8; ++e) {
        __half2 hh = __floats2half2_rn(qf[2 * e], qf[2 * e + 1]);
        qh[e] = *(f16x2*)&hh;
    }
#endif

    // 16-elem q.k dot for one key held as two uint4 of fp16
    auto kdot = [&](uint4 a, uint4 b2) -> float {
#if USE_FDOT2
        float d = 0.f;
        unsigned int aw0 = a.x, aw1 = a.y, aw2 = a.z, aw3 = a.w;
        unsigned int bw0 = b2.x, bw1 = b2.y, bw2 = b2.z, bw3 = b2.w;
        d = __builtin_amdgcn_fdot2(*(const f16x2*)&aw0, qh[0], d, false);
        d = __builtin_amdgcn_fdot2(*(const f16x2*)&aw1, qh[1], d, false);
        d = __builtin_amdgcn_fdot2(*(const f16x2*)&aw2, qh[2], d, false);
        d = __builtin_amdgcn_fdot2(*(const f16x2*)&aw3, qh[3], d, false);
        d = __builtin_amdgcn_fdot2(*(const f16x2*)&bw0, qh[4], d, false);
        d = __builtin_amdgcn_fdot2(*(const f16x2*)&bw1, qh[5], d, false);
        d = __builtin_amdgcn_fdot2(*(const f16x2*)&bw2, qh[6], d, false);
        d = __builtin_amdgcn_fdot2(*(const f16x2*)&bw3, qh[7], d, false);
        return d;
#else
        float kf[16];
        unpack8(a, kf); unpack8(b2, kf + 8);
        float d = 0.f;
#pragma unroll
        for (int e = 0; e < 16; ++e) d = fmaf(qf[e], kf[e], d);
        return d;
#endif
    };

    __syncthreads(); // spos/sal/mcount/sbias visible

    int qx[QPB], qy[QPB], qi[QPB];
    float qa[QPB];
#pragma unroll
    for (int u = 0; u < QPB; ++u) {
        qx[u] = spx[u]; qy[u] = spy[u]; qa[u] = sal[u];
        qi[u] = (r0 + u) & (NN - 1);
    }

    // one scan over all agents, 4 query tests each
    {
        const int2* pb = (const int2*)(positions + (size_t)b * NN * 2);
        const float* ab = alive + (size_t)b * NN;
#pragma unroll
        for (int u = 0; u < NN / 256; ++u) {
            int j = u * 256 + tid;
            int2 pj = pb[j];
            float aj = ab[j];
            if (aj > 0.5f) {
                int packed = j | (pj.x << 16) | (pj.y << 24);
#pragma unroll
                for (int qn = 0; qn < QPB; ++qn) {
                    int dx = pj.x - qx[qn]; dx = dx < 0 ? -dx : dx;
                    int dy = pj.y - qy[qn]; dy = dy < 0 ? -dy : dy;
                    int ch = dx > dy ? dx : dy;
                    if (ch <= RWIN && j != qi[qn] && qa[qn] > 0.5f) {
                        int slot = atomicAdd(&mcount[qn], 1);
                        if (slot < CAND_PQ) cand[qn][slot] = packed;
                    }
                }
            }
        }
    }
    __syncthreads();
    int M = mcount[qq]; if (M > CAND_PQ) M = CAND_PQ;
    const int pix = qx[qq], piy = qy[qq];

    float l = 0.f;
    float o[16];
#pragma unroll
    for (int e = 0; e < 16; ++e) o[e] = 0.f;

    if (s == 0) { // patch column: always allowed, no bias; keeps l>0 for dead queries
        const uint4* kr = (const uint4*)(kb + (size_t)NN * DM + h * DK);
        uint4 ka = kr[0], kb4 = kr[1];
        const uint4* vr = (const uint4*)(vb + (size_t)NN * DM + h * DK);
        uint4 va = vr[0], vb4 = vr[1];
        float d = kdot(ka, kb4);
        float vf[16];
        unpack8(va, vf); unpack8(vb4, vf + 8);
        float p = __expf(d);
        l += p;
#pragma unroll
        for (int e = 0; e < 16; ++e) o[e] = fmaf(p, vf[e], o[e]);
    }

    // 2-key software-pipelined gather: issue all loads for the pair, then compute
    for (int t = s; t < M; t += 16) {
        const int t1 = t + 8;
        const bool has1 = t1 < M;
        int packed0 = cand[qq][t];
        int packed1 = has1 ? cand[qq][t1] : packed0;
        int j0 = packed0 & 0xFFFF;
        int j1 = packed1 & 0xFFFF;

        const uint4* kr0 = (const uint4*)(kb + (size_t)j0 * DM + h * DK);
        const uint4* vr0 = (const uint4*)(vb + (size_t)j0 * DM + h * DK);
        const uint4* kr1 = (const uint4*)(kb + (size_t)j1 * DM + h * DK);
        const uint4* vr1 = (const uint4*)(vb + (size_t)j1 * DM + h * DK);
        uint4 k0a = kr0[0], k0b = kr0[1];
        uint4 v0a = vr0[0], v0b = vr0[1];
        uint4 k1a = kr1[0], k1b = kr1[1];
        uint4 v1a = vr1[0], v1b = vr1[1];

        // key 0
        {
            float d = kdot(k0a, k0b);
            float vf[16];
            unpack8(v0a, vf); unpack8(v0b, vf + 8);
            int pjx = (packed0 >> 16) & 0xFF;
            int pjy = (packed0 >> 24) & 0xFF;
            float bias = sbias[h * 81 + (pjx - pix + RWIN) * 9 + (pjy - piy + RWIN)];
            float p = __expf(d + bias);
            l += p;
#pragma unroll
            for (int e = 0; e < 16; ++e) o[e] = fmaf(p, vf[e], o[e]);
        }
        // key 1
        if (has1) {
            float d = kdot(k1a, k1b);
            float vf[16];
            unpack8(v1a, vf); unpack8(v1b, vf + 8);
            int pjx = (packed1 >> 16) & 0xFF;
            int pjy = (packed1 >> 24) & 0xFF;
            float bias = sbias[h * 81 + (pjx - pix + RWIN) * 9 + (pjy - piy + RWIN)];
            float p = __expf(d + bias);
            l += p;
#pragma unroll
            for (int e = 0; e < 16; ++e) o[e] = fmaf(p, vf[e], o[e]);
        }
    }

    // in-wave reduction over the 8 key-slot lanes: reduce + redistribute.
    // lane s ends with fully-reduced output elements {2s, 2s+1}.
    float r2_0, r2_1;
    {
        float r8[8];
        const bool hi4 = (s & 4) != 0;
#pragma unroll
        for (int e = 0; e < 8; ++e) {
            float a = o[e]     + __shfl_xor(o[e],     4, 64);
            float bq_ = o[e + 8] + __shfl_xor(o[e + 8], 4, 64);
            r8[e] = hi4 ? bq_ : a;
        }
        float r4[4];
        const bool hi2 = (s & 2) != 0;
#pragma unroll
        for (int e = 0; e < 4; ++e) {
            float a = r8[e]     + __shfl_xor(r8[e],     2, 64);
            float bq_ = r8[e + 4] + __shfl_xor(r8[e + 4], 2, 64);
            r4[e] = hi2 ? bq_ : a;
        }
        const bool hi1 = (s & 1) != 0;
#pragma unroll
        for (int e = 0; e < 2; ++e) {
            float a = r4[e]     + __shfl_xor(r4[e],     1, 64);
            float bq_ = r4[e + 2] + __shfl_xor(r4[e + 2], 1, 64);
            float r = hi1 ? bq_ : a;
            if (e == 0) r2_0 = r; else r2_1 = r;
        }
        l += __shfl_xor(l, 1, 64);
        l += __shfl_xor(l, 2, 64);
        l += __shfl_xor(l, 4, 64);
    }
    {
        float linv = 1.f / l;
        float2 st;
        st.x = r2_0 * linv;
        st.y = r2_1 * linv;
        *((float2*)&srow[qq][h * DK + s * 2]) = st;  // offset 2*l6: contiguous, conflict-free
    }
    __syncthreads();

    // ---- cooperative output projection: Wo read once per block ----
    // wave wv owns Wo rows [32wv, 32wv+32); lane: ks = l6>>5 (16-row half),
    // m = l6&31 (cols 4m..4m+3). Each w4 load feeds all 4 queries.
    {
        const int wv = qq;
        const int ks = l6 >> 5;
        const int m  = l6 & 31;
        const int kbase = wv * 32 + ks * 16;
        float4 acc[QPB];
#pragma unroll
        for (int oq = 0; oq < QPB; ++oq) acc[oq] = make_float4(0.f, 0.f, 0.f, 0.f);
#pragma unroll
        for (int r = 0; r < 16; ++r) {
            const int kk = kbase + r;
            float4 w4 = *((const float4*)(Wo + (size_t)kk * DM + m * 4));
#pragma unroll
            for (int oq = 0; oq < QPB; ++oq) {
                float sv = srow[oq][kk];   // broadcast within half-wave
                acc[oq].x = fmaf(sv, w4.x, acc[oq].x);
                acc[oq].y = fmaf(sv, w4.y, acc[oq].y);
                acc[oq].z = fmaf(sv, w4.z, acc[oq].z);
                acc[oq].w = fmaf(sv, w4.w, acc[oq].w);
            }
        }
        // fold the two 16-row halves (ks=0/1) via xor-shuffle across lane 32
#pragma unroll
        for (int oq = 0; oq < QPB; ++oq) {
            acc[oq].x += __shfl_xor(acc[oq].x, 32, 64);
            acc[oq].y += __shfl_xor(acc[oq].y, 32, 64);
            acc[oq].z += __shfl_xor(acc[oq].z, 32, 64);
            acc[oq].w += __shfl_xor(acc[oq].w, 32, 64);
        }
        if (ks == 0) {
#pragma unroll
            for (int oq = 0; oq < QPB; ++oq) pw[wv][oq][m] = acc[oq];
        }
    }
    __syncthreads();

    // final cross-wave reduction: 128 threads, one (query, colgroup) each
    if (tid < QPB * 32) {
        const int oq = tid >> 5;
        const int m  = tid & 31;
        float4 s0 = pw[0][oq][m], s1 = pw[1][oq][m];
        float4 s2 = pw[2][oq][m], s3 = pw[3][oq][m];
        float ga = sal[oq] > 0.5f ? 1.f : 0.f;
        float4 b4 = *((const float4*)(bo + m * 4));
        float4 r;
        r.x = (s0.x + s1.x + s2.x + s3.x + b4.x) * ga;
        r.y = (s0.y + s1.y + s2.y + s3.y + b4.y) * ga;
        r.z = (s0.z + s1.z + s2.z + s3.z + b4.z) * ga;
        r.w = (s0.w + s1.w + s2.w + s3.w + b4.w) * ga;
        ((float4*)(out + (size_t)(r0 + oq) * DM))[m] = r;
    }
}

extern "C" void kernel_launch(void* const* d_in, const int* in_sizes, int n_in,
                              void* d_out, int out_size, void* d_ws, size_t ws_size,
                              hipStream_t stream) {
    const float* z         = (const float*)d_in[0];
    const float* patch     = (const float*)d_in[1];
    const int*   positions = (const int*)d_in[2];
    const float* alive     = (const float*)d_in[3];
    const float* Wq        = (const float*)d_in[4];
    const float* bq        = (const float*)d_in[5];
    const float* Wk        = (const float*)d_in[6];
    const float* bk        = (const float*)d_in[7];
    const float* Wv        = (const float*)d_in[8];
    const float* bv        = (const float*)d_in[9];
    const float* Wo        = (const float*)d_in[10];
    const float* bo        = (const float*)d_in[11];
    const float* rel_bias  = (const float*)d_in[12];
    float* out = (float*)d_out;

    char* ws = (char*)d_ws;
    size_t off = 0;
    auto alloc = [&](size_t bytes) -> void* {
        void* p = ws + off;
        off += (bytes + 255) & ~(size_t)255;
        return p;
    };
    float*  q = (float*)alloc((size_t)BB * NN * DM * 4);
    __half* k = (__half*)alloc((size_t)BB * NP1 * DM * 2);
    __half* v = (__half*)alloc((size_t)BB * NP1 * DM * 2);

    qkv_kernel<<<(BB * NP1 + QKV_ROWS - 1) / QKV_ROWS, 384, 0, stream>>>(z, patch, Wq, bq, Wk, bk, Wv, bv, q, k, v);
    attn_out_kernel<<<(BB * NN) / QPB, 256, 0, stream>>>(q, k, v, positions, alive, rel_bias, Wo, bo, out);
}

// Round 6
// 109.126 us; speedup vs baseline: 1.0815x; 1.0625x over previous
//
#include <hip/hip_runtime.h>
#include <hip/hip_fp16.h>
#include <math.h>

#define BB 2
#define NN 2048
#define NP1 2049
#define DM 128
#define NH 8
#define DK 16
#define RWIN 4
#define GRID_W 64
#define QPB 4        /* queries per attn block */
#define CAND_PQ 160  /* per-query candidate cap; binom mean ~36, sd ~6 */

/* v_dot2_f32_f16: 2 fp16 products + f32 accumulate per instruction */
#if defined(__has_builtin)
#  if __has_builtin(__builtin_amdgcn_fdot2)
#    define USE_FDOT2 1
#  endif
#endif
#ifndef USE_FDOT2
#  define USE_FDOT2 0
#endif
typedef _Float16 f16x2 __attribute__((ext_vector_type(2)));

__device__ __forceinline__ void unpack8(uint4 r, float* f) {
    float2 t;
    t = __half22float2(*(const __half2*)&r.x); f[0] = t.x; f[1] = t.y;
    t = __half22float2(*(const __half2*)&r.y); f[2] = t.x; f[3] = t.y;
    t = __half22float2(*(const __half2*)&r.z); f[4] = t.x; f[5] = t.y;
    t = __half22float2(*(const __half2*)&r.w); f[6] = t.x; f[7] = t.y;
}

// ---------------- QKV projection ----------------
// R15: wave-level k-split (what R13 should have been). R13 split kk by
// tid>>7 half-groups, but each half-group was 2 WAVES reading identical W
// streams -> no traffic reduction, pure overhead. Now each of the 6 waves
// owns a unique (mat, kk-half): mat = wave>>1, kh = wave&1. No two waves
// read the same W bytes: per-block W port traffic 768KB -> 384KB with
// UNCHANGED occupancy (384T, 513 blocks, 12 waves/CU). Lane: cg = lane&31
// (4 cols), rh = lane>>5 (rows rh*4..rh*4+3), 16 acc VGPRs. kh=1 wave
// writes partials to 12KB LDS; kh=0 wave adds, applies bias, stores.

#define QKV_ROWS 8

__global__ __launch_bounds__(384) void qkv_kernel(
    const float* __restrict__ z, const float* __restrict__ patch,
    const float* __restrict__ Wq, const float* __restrict__ bq,
    const float* __restrict__ Wk, const float* __restrict__ bk,
    const float* __restrict__ Wv, const float* __restrict__ bv,
    float* __restrict__ q, __half* __restrict__ k, __half* __restrict__ v) {
    __shared__ float zrow[QKV_ROWS][DM];
    __shared__ float pacc[3][QKV_ROWS][DM];   // kh=1 partial sums
    const int tid = threadIdx.x;
    const int wave = tid >> 6;         // 0..5
    const int mat  = wave >> 1;        // 0=q 1=k 2=v, wave-uniform
    const int kh   = wave & 1;         // kk half, wave-uniform
    const int lane = tid & 63;
    const int cg = lane & 31;          // cols cg*4..cg*4+3
    const int rh = lane >> 5;          // rows rh*4 .. rh*4+3
    const int r0 = blockIdx.x * QKV_ROWS;
    const int NROWS = BB * NP1;

    if (tid < QKV_ROWS * DM / 4) {
        int r = tid >> 5, q4 = tid & 31;
        int row = r0 + r;
        float4 val = make_float4(0.f, 0.f, 0.f, 0.f);
        if (row < NROWS) {
            int b = row / NP1, ti = row % NP1;
            const float* src = (ti < NN) ? (z + ((size_t)b * NN + ti) * DM)
                                         : (patch + (size_t)b * DM);
            val = ((const float4*)src)[q4];
        }
        *((float4*)&zrow[r][q4 * 4]) = val;
    }
    __syncthreads();

    const float* W    = (mat == 0) ? Wq : (mat == 1) ? Wk : Wv;
    const float* bias = (mat == 0) ? bq : (mat == 1) ? bk : bv;
    const int k0 = kh * 64;
    const int row0 = rh * 4;

    float4 acc[4];
#pragma unroll
    for (int r = 0; r < 4; ++r) acc[r] = make_float4(0.f, 0.f, 0.f, 0.f);

#pragma unroll 2
    for (int kk4 = k0; kk4 < k0 + 64; kk4 += 4) {
        float4 zv0 = *((const float4*)&zrow[row0 + 0][kk4]);
        float4 zv1 = *((const float4*)&zrow[row0 + 1][kk4]);
        float4 zv2 = *((const float4*)&zrow[row0 + 2][kk4]);
        float4 zv3 = *((const float4*)&zrow[row0 + 3][kk4]);
        const float* zp0 = (const float*)&zv0;
        const float* zp1 = (const float*)&zv1;
        const float* zp2 = (const float*)&zv2;
        const float* zp3 = (const float*)&zv3;
#pragma unroll
        for (int t = 0; t < 4; ++t) {
            float4 w4 = *((const float4*)(W + (size_t)(kk4 + t) * DM + cg * 4));
            float z0 = zp0[t], z1 = zp1[t], z2 = zp2[t], z3 = zp3[t];
            acc[0].x = fmaf(z0, w4.x, acc[0].x); acc[0].y = fmaf(z0, w4.y, acc[0].y);
            acc[0].z = fmaf(z0, w4.z, acc[0].z); acc[0].w = fmaf(z0, w4.w, acc[0].w);
            acc[1].x = fmaf(z1, w4.x, acc[1].x); acc[1].y = fmaf(z1, w4.y, acc[1].y);
            acc[1].z = fmaf(z1, w4.z, acc[1].z); acc[1].w = fmaf(z1, w4.w, acc[1].w);
            acc[2].x = fmaf(z2, w4.x, acc[2].x); acc[2].y = fmaf(z2, w4.y, acc[2].y);
            acc[2].z = fmaf(z2, w4.z, acc[2].z); acc[2].w = fmaf(z2, w4.w, acc[2].w);
            acc[3].x = fmaf(z3, w4.x, acc[3].x); acc[3].y = fmaf(z3, w4.y, acc[3].y);
            acc[3].z = fmaf(z3, w4.z, acc[3].z); acc[3].w = fmaf(z3, w4.w, acc[3].w);
        }
    }

    if (kh == 1) {
#pragma unroll
        for (int r = 0; r < 4; ++r)
            *((float4*)&pacc[mat][row0 + r][cg * 4]) = acc[r];
    }
    __syncthreads();

    if (kh == 0) {
        float4 b4 = *((const float4*)(bias + cg * 4));
#pragma unroll
        for (int r = 0; r < 4; ++r) {
            int row = r0 + row0 + r;
            if (row >= NROWS) break;
            float4 p = *((const float4*)&pacc[mat][row0 + r][cg * 4]);
            float4 val;
            val.x = acc[r].x + p.x + b4.x; val.y = acc[r].y + p.y + b4.y;
            val.z = acc[r].z + p.z + b4.z; val.w = acc[r].w + p.w + b4.w;
            int b = row / NP1, ti = row % NP1;
            if (mat == 0) {
                if (ti < NN) ((float4*)(q + ((size_t)b * NN + ti) * DM))[cg] = val;
            } else {
                __half2 p0h = __floats2half2_rn(val.x, val.y);
                __half2 p1h = __floats2half2_rn(val.z, val.w);
                uint2 st;
                st.x = *(unsigned int*)&p0h;
                st.y = *(unsigned int*)&p1h;
                __half* dst = ((mat == 1) ? k : v) + ((size_t)b * NP1 + ti) * DM;
                ((uint2*)dst)[cg] = st;
            }
        }
    }
}

// ---------------- fused: 4-query scan + sparse attention + out-proj ----------------
// (unchanged this round -- isolating the qkv wave-level k-split)
// grid 1024 blocks, 256 threads = 4 queries x 8 heads x 8 key-slots.
// fp16 K/V uint4 gathers; no-max softmax; slot-reduce via xor-shuffle tree
// (R10); cooperative Wo out-projection, Wo read once/block (R11, -5.2us);
// 2-key software-pipelined gather (R12); fdot2 K-dot (R14).

__global__ __launch_bounds__(256) void attn_out_kernel(
    const float* __restrict__ q, const __half* __restrict__ k, const __half* __restrict__ v,
    const int* __restrict__ positions, const float* __restrict__ alive,
    const float* __restrict__ rel_bias, const float* __restrict__ Wo,
    const float* __restrict__ bo, float* __restrict__ out) {
    const int tid = threadIdx.x;
    const int qq = tid >> 6;          // 0..3 query in group (= wave id)
    const int l6 = tid & 63;
    const int h = l6 >> 3;            // 0..7 head
    const int s = l6 & 7;             // 0..7 key slot
    const int r0 = blockIdx.x * QPB;  // global query base (same batch: NN%QPB==0)
    const int b = r0 >> 11;
    const int bi = r0 + qq;

    __shared__ float sbias[NH * 81];
    __shared__ int   spx[QPB], spy[QPB];
    __shared__ float sal[QPB];
    __shared__ int   mcount[QPB];
    __shared__ int   cand[QPB][CAND_PQ];
    __shared__ float srow[QPB][DM];        // normalized attention output per query
    __shared__ float4 pw[QPB][QPB][32];    // [wave][query][colgroup] out-proj partials

    if (tid < QPB) {
        mcount[tid] = 0;
        int gbi = r0 + tid;
        spx[tid] = positions[gbi * 2 + 0];
        spy[tid] = positions[gbi * 2 + 1];
        sal[tid] = alive[gbi];
    }
    if (tid < NH * 81 / 4) ((float4*)sbias)[tid] = ((const float4*)rel_bias)[tid];

    const __half* kb = k + (size_t)b * NP1 * DM;
    const __half* vb = v + (size_t)b * NP1 * DM;

    // q segment for (query qq, head h), pre-scaled by 1/sqrt(dk)
    float qf[16];
    {
        const float4* qr = (const float4*)(q + (size_t)bi * DM + h * DK);
#pragma unroll
        for (int e = 0; e < 4; ++e) {
            float4 t4 = qr[e];
            qf[e * 4 + 0] = t4.x * 0.25f; qf[e * 4 + 1] = t4.y * 0.25f;
            qf[e * 4 + 2] = t4.z * 0.25f; qf[e * 4 + 3] = t4.w * 0.25f;
        }
    }
#if USE_FDOT2
    f16x2 qh[8];
#pragma unroll
    for (int e = 0; e < 8; ++e) {
        __half2 hh = __floats2half2_rn(qf[2 * e], qf[2 * e + 1]);
        qh[e] = *(f16x2*)&hh;
    }
#endif

    // 16-elem q.k dot for one key held as two uint4 of fp16
    auto kdot = [&](uint4 a, uint4 b2) -> float {
#if USE_FDOT2
        float d = 0.f;
        unsigned int aw0 = a.x, aw1 = a.y, aw2 = a.z, aw3 = a.w;
        unsigned int bw0 = b2.x, bw1 = b2.y, bw2 = b2.z, bw3 = b2.w;
        d = __builtin_amdgcn_fdot2(*(const f16x2*)&aw0, qh[0], d, false);
        d = __builtin_amdgcn_fdot2(*(const f16x2*)&aw1, qh[1], d, false);
        d = __builtin_amdgcn_fdot2(*(const f16x2*)&aw2, qh[2], d, false);
        d = __builtin_amdgcn_fdot2(*(const f16x2*)&aw3, qh[3], d, false);
        d = __builtin_amdgcn_fdot2(*(const f16x2*)&bw0, qh[4], d, false);
        d = __builtin_amdgcn_fdot2(*(const f16x2*)&bw1, qh[5], d, false);
        d = __builtin_amdgcn_fdot2(*(const f16x2*)&bw2, qh[6], d, false);
        d = __builtin_amdgcn_fdot2(*(const f16x2*)&bw3, qh[7], d, false);
        return d;
#else
        float kf[16];
        unpack8(a, kf); unpack8(b2, kf + 8);
        float d = 0.f;
#pragma unroll
        for (int e = 0; e < 16; ++e) d = fmaf(qf[e], kf[e], d);
        return d;
#endif
    };

    __syncthreads(); // spos/sal/mcount/sbias visible

    int qx[QPB], qy[QPB], qi[QPB];
    float qa[QPB];
#pragma unroll
    for (int u = 0; u < QPB; ++u) {
        qx[u] = spx[u]; qy[u] = spy[u]; qa[u] = sal[u];
        qi[u] = (r0 + u) & (NN - 1);
    }

    // one scan over all agents, 4 query tests each
    {
        const int2* pb = (const int2*)(positions + (size_t)b * NN * 2);
        const float* ab = alive + (size_t)b * NN;
#pragma unroll
        for (int u = 0; u < NN / 256; ++u) {
            int j = u * 256 + tid;
            int2 pj = pb[j];
            float aj = ab[j];
            if (aj > 0.5f) {
                int packed = j | (pj.x << 16) | (pj.y << 24);
#pragma unroll
                for (int qn = 0; qn < QPB; ++qn) {
                    int dx = pj.x - qx[qn]; dx = dx < 0 ? -dx : dx;
                    int dy = pj.y - qy[qn]; dy = dy < 0 ? -dy : dy;
                    int ch = dx > dy ? dx : dy;
                    if (ch <= RWIN && j != qi[qn] && qa[qn] > 0.5f) {
                        int slot = atomicAdd(&mcount[qn], 1);
                        if (slot < CAND_PQ) cand[qn][slot] = packed;
                    }
                }
            }
        }
    }
    __syncthreads();
    int M = mcount[qq]; if (M > CAND_PQ) M = CAND_PQ;
    const int pix = qx[qq], piy = qy[qq];

    float l = 0.f;
    float o[16];
#pragma unroll
    for (int e = 0; e < 16; ++e) o[e] = 0.f;

    if (s == 0) { // patch column: always allowed, no bias; keeps l>0 for dead queries
        const uint4* kr = (const uint4*)(kb + (size_t)NN * DM + h * DK);
        uint4 ka = kr[0], kb4 = kr[1];
        const uint4* vr = (const uint4*)(vb + (size_t)NN * DM + h * DK);
        uint4 va = vr[0], vb4 = vr[1];
        float d = kdot(ka, kb4);
        float vf[16];
        unpack8(va, vf); unpack8(vb4, vf + 8);
        float p = __expf(d);
        l += p;
#pragma unroll
        for (int e = 0; e < 16; ++e) o[e] = fmaf(p, vf[e], o[e]);
    }

    // 2-key software-pipelined gather: issue all loads for the pair, then compute
    for (int t = s; t < M; t += 16) {
        const int t1 = t + 8;
        const bool has1 = t1 < M;
        int packed0 = cand[qq][t];
        int packed1 = has1 ? cand[qq][t1] : packed0;
        int j0 = packed0 & 0xFFFF;
        int j1 = packed1 & 0xFFFF;

        const uint4* kr0 = (const uint4*)(kb + (size_t)j0 * DM + h * DK);
        const uint4* vr0 = (const uint4*)(vb + (size_t)j0 * DM + h * DK);
        const uint4* kr1 = (const uint4*)(kb + (size_t)j1 * DM + h * DK);
        const uint4* vr1 = (const uint4*)(vb + (size_t)j1 * DM + h * DK);
        uint4 k0a = kr0[0], k0b = kr0[1];
        uint4 v0a = vr0[0], v0b = vr0[1];
        uint4 k1a = kr1[0], k1b = kr1[1];
        uint4 v1a = vr1[0], v1b = vr1[1];

        // key 0
        {
            float d = kdot(k0a, k0b);
            float vf[16];
            unpack8(v0a, vf); unpack8(v0b, vf + 8);
            int pjx = (packed0 >> 16) & 0xFF;
            int pjy = (packed0 >> 24) & 0xFF;
            float bias = sbias[h * 81 + (pjx - pix + RWIN) * 9 + (pjy - piy + RWIN)];
            float p = __expf(d + bias);
            l += p;
#pragma unroll
            for (int e = 0; e < 16; ++e) o[e] = fmaf(p, vf[e], o[e]);
        }
        // key 1
        if (has1) {
            float d = kdot(k1a, k1b);
            float vf[16];
            unpack8(v1a, vf); unpack8(v1b, vf + 8);
            int pjx = (packed1 >> 16) & 0xFF;
            int pjy = (packed1 >> 24) & 0xFF;
            float bias = sbias[h * 81 + (pjx - pix + RWIN) * 9 + (pjy - piy + RWIN)];
            float p = __expf(d + bias);
            l += p;
#pragma unroll
            for (int e = 0; e < 16; ++e) o[e] = fmaf(p, vf[e], o[e]);
        }
    }

    // in-wave reduction over the 8 key-slot lanes: reduce + redistribute.
    // lane s ends with fully-reduced output elements {2s, 2s+1}.
    float r2_0, r2_1;
    {
        float r8[8];
        const bool hi4 = (s & 4) != 0;
#pragma unroll
        for (int e = 0; e < 8; ++e) {
            float a = o[e]     + __shfl_xor(o[e],     4, 64);
            float bq_ = o[e + 8] + __shfl_xor(o[e + 8], 4, 64);
            r8[e] = hi4 ? bq_ : a;
        }
        float r4[4];
        const bool hi2 = (s & 2) != 0;
#pragma unroll
        for (int e = 0; e < 4; ++e) {
            float a = r8[e]     + __shfl_xor(r8[e],     2, 64);
            float bq_ = r8[e + 4] + __shfl_xor(r8[e + 4], 2, 64);
            r4[e] = hi2 ? bq_ : a;
        }
        const bool hi1 = (s & 1) != 0;
#pragma unroll
        for (int e = 0; e < 2; ++e) {
            float a = r4[e]     + __shfl_xor(r4[e],     1, 64);
            float bq_ = r4[e + 2] + __shfl_xor(r4[e + 2], 1, 64);
            float r = hi1 ? bq_ : a;
            if (e == 0) r2_0 = r; else r2_1 = r;
        }
        l += __shfl_xor(l, 1, 64);
        l += __shfl_xor(l, 2, 64);
        l += __shfl_xor(l, 4, 64);
    }
    {
        float linv = 1.f / l;
        float2 st;
        st.x = r2_0 * linv;
        st.y = r2_1 * linv;
        *((float2*)&srow[qq][h * DK + s * 2]) = st;  // offset 2*l6: contiguous, conflict-free
    }
    __syncthreads();

    // ---- cooperative output projection: Wo read once per block ----
    // wave wv owns Wo rows [32wv, 32wv+32); lane: ks = l6>>5 (16-row half),
    // m = l6&31 (cols 4m..4m+3). Each w4 load feeds all 4 queries.
    {
        const int wv = qq;
        const int ks = l6 >> 5;
        const int m  = l6 & 31;
        const int kbase = wv * 32 + ks * 16;
        float4 acc[QPB];
#pragma unroll
        for (int oq = 0; oq < QPB; ++oq) acc[oq] = make_float4(0.f, 0.f, 0.f, 0.f);
#pragma unroll
        for (int r = 0; r < 16; ++r) {
            const int kk = kbase + r;
            float4 w4 = *((const float4*)(Wo + (size_t)kk * DM + m * 4));
#pragma unroll
            for (int oq = 0; oq < QPB; ++oq) {
                float sv = srow[oq][kk];   // broadcast within half-wave
                acc[oq].x = fmaf(sv, w4.x, acc[oq].x);
                acc[oq].y = fmaf(sv, w4.y, acc[oq].y);
                acc[oq].z = fmaf(sv, w4.z, acc[oq].z);
                acc[oq].w = fmaf(sv, w4.w, acc[oq].w);
            }
        }
        // fold the two 16-row halves (ks=0/1) via xor-shuffle across lane 32
#pragma unroll
        for (int oq = 0; oq < QPB; ++oq) {
            acc[oq].x += __shfl_xor(acc[oq].x, 32, 64);
            acc[oq].y += __shfl_xor(acc[oq].y, 32, 64);
            acc[oq].z += __shfl_xor(acc[oq].z, 32, 64);
            acc[oq].w += __shfl_xor(acc[oq].w, 32, 64);
        }
        if (ks == 0) {
#pragma unroll
            for (int oq = 0; oq < QPB; ++oq) pw[wv][oq][m] = acc[oq];
        }
    }
    __syncthreads();

    // final cross-wave reduction: 128 threads, one (query, colgroup) each
    if (tid < QPB * 32) {
        const int oq = tid >> 5;
        const int m  = tid & 31;
        float4 s0 = pw[0][oq][m], s1 = pw[1][oq][m];
        float4 s2 = pw[2][oq][m], s3 = pw[3][oq][m];
        float ga = sal[oq] > 0.5f ? 1.f : 0.f;
        float4 b4 = *((const float4*)(bo + m * 4));
        float4 r;
        r.x = (s0.x + s1.x + s2.x + s3.x + b4.x) * ga;
        r.y = (s0.y + s1.y + s2.y + s3.y + b4.y) * ga;
        r.z = (s0.z + s1.z + s2.z + s3.z + b4.z) * ga;
        r.w = (s0.w + s1.w + s2.w + s3.w + b4.w) * ga;
        ((float4*)(out + (size_t)(r0 + oq) * DM))[m] = r;
    }
}

extern "C" void kernel_launch(void* const* d_in, const int* in_sizes, int n_in,
                              void* d_out, int out_size, void* d_ws, size_t ws_size,
                              hipStream_t stream) {
    const float* z         = (const float*)d_in[0];
    const float* patch     = (const float*)d_in[1];
    const int*   positions = (const int*)d_in[2];
    const float* alive     = (const float*)d_in[3];
    const float* Wq        = (const float*)d_in[4];
    const float* bq        = (const float*)d_in[5];
    const float* Wk        = (const float*)d_in[6];
    const float* bk        = (const float*)d_in[7];
    const float* Wv        = (const float*)d_in[8];
    const float* bv        = (const float*)d_in[9];
    const float* Wo        = (const float*)d_in[10];
    const float* bo        = (const float*)d_in[11];
    const float* rel_bias  = (const float*)d_in[12];
    float* out = (float*)d_out;

    char* ws = (char*)d_ws;
    size_t off = 0;
    auto alloc = [&](size_t bytes) -> void* {
        void* p = ws + off;
        off += (bytes + 255) & ~(size_t)255;
        return p;
    };
    float*  q = (float*)alloc((size_t)BB * NN * DM * 4);
    __half* k = (__half*)alloc((size_t)BB * NP1 * DM * 2);
    __half* v = (__half*)alloc((size_t)BB * NP1 * DM * 2);

    qkv_kernel<<<(BB * NP1 + QKV_ROWS - 1) / QKV_ROWS, 384, 0, stream>>>(z, patch, Wq, bq, Wk, bk, Wv, bv, q, k, v);
    attn_out_kernel<<<(BB * NN) / QPB, 256, 0, stream>>>(q, k, v, positions, alive, rel_bias, Wo, bo, out);
}